// Round 1
// baseline (330.144 us; speedup 1.0000x reference)
//
#include <hip/hip_runtime.h>
#include <math.h>

#define NCAND 24

static __device__ __forceinline__ float xprod(float ux, float uz, float vx, float vz) {
    return ux * vz - uz * vx;
}

// Monotone substitute for atan2f(z, x): strictly increasing with the true angle
// over (-pi, pi], range (-2, 2]. Exact ties in angle contribute zero cross
// product in the shoelace, so sort-order differences at ties don't change area.
static __device__ __forceinline__ float pseudo_angle(float x, float z) {
    float d = fabsf(x) + fabsf(z);
    float p = z / fmaxf(d, 1e-30f);
    return (x >= 0.0f) ? p : (copysignf(2.0f, z) - p);
}

__global__ __launch_bounds__(256) void iou3d_kernel(
    const float* __restrict__ pred,
    const float* __restrict__ tgt,
    float* __restrict__ out,
    int N)
{
    int i = blockIdx.x * blockDim.x + threadIdx.x;
    if (i >= N) return;

    const float* pa = pred + (long)i * 7;
    const float* pb = tgt  + (long)i * 7;

    float a_x  = pa[0], a_y = pa[1], a_z = pa[2];
    float a_dx = pa[3], a_dy = pa[4], a_dz = pa[5], a_ry = pa[6];
    float b_x  = pb[0], b_y = pb[1], b_z = pb[2];
    float b_dx = pb[3], b_dy = pb[4], b_dz = pb[5], b_ry = pb[6];

    // height overlap (reference: y axis negated, clip at 0)
    float min_h_a = -(a_y + a_dy * 0.5f);
    float max_h_a = -(a_y - a_dy * 0.5f);
    float min_h_b = -(b_y + b_dy * 0.5f);
    float max_h_b = -(b_y - b_dy * 0.5f);
    float h_ov = fmaxf(fminf(max_h_a, max_h_b) - fmaxf(min_h_a, min_h_b), 0.0f);

    // reference quirk: h_a0 is box 0's pred height for ALL rows
    float y0 = pred[1], dy0 = pred[4];
    float h_a0 = (-(y0 - dy0 * 0.5f)) - (-(y0 + dy0 * 0.5f));

    // rotated BEV corners
    float Axc[4], Azc[4], Bxc[4], Bzc[4];
    {
        float c = __cosf(a_ry), s = __sinf(a_ry);
        float hx = a_dx * 0.5f, hz = a_dz * 0.5f;
        const float lx[4] = { hx, -hx, -hx, hx };
        const float lz[4] = { hz, hz, -hz, -hz };
        #pragma unroll
        for (int k = 0; k < 4; k++) {
            Axc[k] = lx[k] * c - lz[k] * s + a_x;
            Azc[k] = lx[k] * s + lz[k] * c + a_z;
        }
    }
    {
        float c = __cosf(b_ry), s = __sinf(b_ry);
        float hx = b_dx * 0.5f, hz = b_dz * 0.5f;
        const float lx[4] = { hx, -hx, -hx, hx };
        const float lz[4] = { hz, hz, -hz, -hz };
        #pragma unroll
        for (int k = 0; k < 4; k++) {
            Bxc[k] = lx[k] * c - lz[k] * s + b_x;
            Bzc[k] = lx[k] * s + lz[k] * c + b_z;
        }
    }

    // quad areas (shoelace, matches _quad_area)
    float area_a = 0.0f, area_b = 0.0f;
    #pragma unroll
    for (int k = 0; k < 4; k++) {
        int kn = (k + 1) & 3;
        area_a += xprod(Axc[k], Azc[k], Axc[kn], Azc[kn]);
        area_b += xprod(Bxc[k], Bzc[k], Bxc[kn], Bzc[kn]);
    }
    area_a = 0.5f * fabsf(area_a);
    area_b = 0.5f * fabsf(area_b);

    // --- candidate points: A corners (0-3), B corners (4-7), edge ipts (8-23)
    float px[NCAND], pz[NCAND];
    unsigned vmask = 0;

    #pragma unroll
    for (int k = 0; k < 4; k++) {
        px[k]     = Axc[k]; pz[k]     = Azc[k];
        px[4 + k] = Bxc[k]; pz[4 + k] = Bzc[k];
    }

    // point-in-quad tests (epsilon 1e-6, either orientation)
    #pragma unroll
    for (int k = 0; k < 4; k++) {
        bool allpos = true, allneg = true;
        #pragma unroll
        for (int e = 0; e < 4; e++) {
            int en = (e + 1) & 3;
            float s = xprod(Bxc[en] - Bxc[e], Bzc[en] - Bzc[e],
                            Axc[k] - Bxc[e], Azc[k] - Bzc[e]);
            allpos = allpos && (s >= -1e-6f);
            allneg = allneg && (s <= 1e-6f);
        }
        if (allpos || allneg) vmask |= (1u << k);

        allpos = true; allneg = true;
        #pragma unroll
        for (int e = 0; e < 4; e++) {
            int en = (e + 1) & 3;
            float s = xprod(Axc[en] - Axc[e], Azc[en] - Azc[e],
                            Bxc[k] - Axc[e], Bzc[k] - Azc[e]);
            allpos = allpos && (s >= -1e-6f);
            allneg = allneg && (s <= 1e-6f);
        }
        if (allpos || allneg) vmask |= (1u << (4 + k));
    }

    // edge-edge intersections (16 pairs)
    #pragma unroll
    for (int ie = 0; ie < 4; ie++) {
        int in_ = (ie + 1) & 3;
        float a1x = Axc[ie], a1z = Azc[ie];
        float dax = Axc[in_] - a1x, daz = Azc[in_] - a1z;
        #pragma unroll
        for (int je = 0; je < 4; je++) {
            int jn = (je + 1) & 3;
            float b1x = Bxc[je], b1z = Bzc[je];
            float dbx = Bxc[jn] - b1x, dbz = Bzc[jn] - b1z;
            float den = xprod(dax, daz, dbx, dbz);
            bool dok = fabsf(den) >= 1e-8f;
            float den_safe = dok ? den : 1.0f;
            float inv = 1.0f / den_safe;
            float wx = b1x - a1x, wz = b1z - a1z;
            float t = xprod(wx, wz, dbx, dbz) * inv;
            float u = xprod(wx, wz, dax, daz) * inv;
            bool ok = dok && (t >= 0.0f) && (t <= 1.0f) && (u >= 0.0f) && (u <= 1.0f);
            int idx = 8 + ie * 4 + je;
            px[idx] = a1x + t * dax;
            pz[idx] = a1z + t * daz;
            if (ok) vmask |= (1u << idx);
        }
    }

    // centroid of valid candidates
    int cnt = __popc(vmask);
    float sx = 0.0f, sz = 0.0f;
    #pragma unroll
    for (int k = 0; k < NCAND; k++) {
        bool v = (vmask >> k) & 1u;
        sx += v ? px[k] : 0.0f;
        sz += v ? pz[k] : 0.0f;
    }
    float cdiv = fmaxf((float)cnt, 1.0f);
    float cx = sx / cdiv, cz = sz / cdiv;

    // rel coords + sort keys (invalid -> 1e9, sorts last like the reference)
    float ang[NCAND];
    #pragma unroll
    for (int k = 0; k < NCAND; k++) {
        float rx_ = px[k] - cx, rz_ = pz[k] - cz;
        px[k] = rx_; pz[k] = rz_;
        bool v = (vmask >> k) & 1u;
        ang[k] = v ? pseudo_angle(rx_, rz_) : 1e9f;
    }

    // fully-unrolled register exchange sort by ang (unstable; ties are
    // zero-area contributions so order at ties doesn't matter)
    #pragma unroll
    for (int ai = 0; ai < NCAND - 1; ai++) {
        #pragma unroll
        for (int bi = ai + 1; bi < NCAND; bi++) {
            bool sw = ang[bi] < ang[ai];
            float ta = sw ? ang[bi] : ang[ai];
            ang[bi] = sw ? ang[ai] : ang[bi]; ang[ai] = ta;
            float tx = sw ? px[bi] : px[ai];
            px[bi] = sw ? px[ai] : px[bi]; px[ai] = tx;
            float tz = sw ? pz[bi] : pz[ai];
            pz[bi] = sw ? pz[ai] : pz[bi]; pz[ai] = tz;
        }
    }

    // shoelace over the first cnt sorted points
    float body = 0.0f;
    #pragma unroll
    for (int k = 0; k < NCAND - 1; k++) {
        float c = xprod(px[k], pz[k], px[k + 1], pz[k + 1]);
        body += (k < cnt - 1) ? c : 0.0f;
    }
    int li = max(cnt - 1, 0);
    float lxv = px[0], lzv = pz[0];
    #pragma unroll
    for (int k = 1; k < NCAND; k++) {
        bool sel = (k == li);
        lxv = sel ? px[k] : lxv;
        lzv = sel ? pz[k] : lzv;
    }
    float closing = xprod(lxv, lzv, px[0], pz[0]);
    float area = 0.5f * fabsf(body + closing);
    area = (cnt >= 3) ? area : 0.0f;

    float overlap3d = area * h_ov;
    float union3d = area_a * h_a0 + area_b * (max_h_b - min_h_b) - overlap3d;
    out[i] = overlap3d / union3d;
}

extern "C" void kernel_launch(void* const* d_in, const int* in_sizes, int n_in,
                              void* d_out, int out_size, void* d_ws, size_t ws_size,
                              hipStream_t stream) {
    const float* pred = (const float*)d_in[0];
    const float* tgt  = (const float*)d_in[1];
    float* out = (float*)d_out;
    int N = in_sizes[0] / 7;
    int block = 256;
    int grid = (N + block - 1) / block;
    hipLaunchKernelGGL(iou3d_kernel, dim3(grid), dim3(block), 0, stream,
                       pred, tgt, out, N);
}

// Round 2
// 74.640 us; speedup vs baseline: 4.4232x; 4.4232x over previous
//
#include <hip/hip_runtime.h>
#include <math.h>

static __device__ __forceinline__ float xprod(float ux, float uz, float vx, float vz) {
    return ux * vz - uz * vx;
}

// One Sutherland-Hodgman clip pass of a convex polygon (CCW) against the
// half-plane left of directed edge (o -> o+e). NIN = max input vertex count
// (compile-time capacity); n = runtime count. All indices are compile-time
// after unrolling, so buffers stay in VGPRs. Returns new count (<= NIN+1).
template<int NIN>
static __device__ __forceinline__ int clip_pass(
    const float (&inx)[8], const float (&inz)[8], int n,
    float ox, float oz, float ex, float ez,
    float (&outx)[8], float (&outz)[8])
{
    float d[NIN];
    #pragma unroll
    for (int i = 0; i < NIN; i++)
        d[i] = xprod(ex, ez, inx[i] - ox, inz[i] - oz);

    bool e0[NIN], e1[NIN];       // emit p_i / emit intersection
    float qx[NIN], qz[NIN];      // intersection points
    int pos0[NIN], pos1[NIN];    // output positions
    int c = 0;
    #pragma unroll
    for (int i = 0; i < NIN; i++) {
        bool active = (i < n);
        bool last = (i == n - 1);
        constexpr int NX = 0; // dummy to keep static succ index in-bounds
        (void)NX;
        float sx = last ? inx[0] : inx[(i + 1 < NIN) ? i + 1 : 0];
        float sz = last ? inz[0] : inz[(i + 1 < NIN) ? i + 1 : 0];
        float ds = last ? d[0]   : d[(i + 1 < NIN) ? i + 1 : 0];
        bool ins  = d[i] >= 0.0f;
        bool inss = ds   >= 0.0f;
        bool crossing = active && (ins != inss);
        float denom = d[i] - ds;
        float t = __fdividef(d[i], (denom == 0.0f) ? 1.0f : denom);
        qx[i] = inx[i] + t * (sx - inx[i]);
        qz[i] = inz[i] + t * (sz - inz[i]);
        e0[i] = active && ins;
        e1[i] = crossing;
        pos0[i] = c; c += e0[i] ? 1 : 0;
        pos1[i] = c; c += e1[i] ? 1 : 0;
    }

    // select-based compaction: slot j takes the item whose prefix-pos == j
    #pragma unroll
    for (int j = 0; j <= NIN && j < 8; j++) {
        float vx = 0.0f, vz = 0.0f;
        #pragma unroll
        for (int i = 0; i < NIN; i++) {
            bool s0 = e0[i] && (pos0[i] == j);
            vx = s0 ? inx[i] : vx;
            vz = s0 ? inz[i] : vz;
            bool s1 = e1[i] && (pos1[i] == j);
            vx = s1 ? qx[i] : vx;
            vz = s1 ? qz[i] : vz;
        }
        outx[j] = vx; outz[j] = vz;
    }
    return c;
}

__global__ __launch_bounds__(256) void iou3d_kernel(
    const float* __restrict__ pred,
    const float* __restrict__ tgt,
    float* __restrict__ out,
    int N)
{
    int i = blockIdx.x * blockDim.x + threadIdx.x;
    if (i >= N) return;

    const float* pa = pred + (long)i * 7;
    const float* pb = tgt  + (long)i * 7;

    float a_x  = pa[0], a_y = pa[1], a_z = pa[2];
    float a_dx = pa[3], a_dy = pa[4], a_dz = pa[5], a_ry = pa[6];
    float b_x  = pb[0], b_y = pb[1], b_z = pb[2];
    float b_dx = pb[3], b_dy = pb[4], b_dz = pb[5], b_ry = pb[6];

    // height overlap (reference: y axis negated, clip at 0)
    float min_h_a = -(a_y + a_dy * 0.5f);
    float max_h_a = -(a_y - a_dy * 0.5f);
    float min_h_b = -(b_y + b_dy * 0.5f);
    float max_h_b = -(b_y - b_dy * 0.5f);
    float h_ov = fmaxf(fminf(max_h_a, max_h_b) - fmaxf(min_h_a, min_h_b), 0.0f);

    // reference quirk: h_a0 is box 0's pred height for ALL rows
    float y0 = pred[1], dy0 = pred[4];
    float h_a0 = (-(y0 - dy0 * 0.5f)) - (-(y0 + dy0 * 0.5f));

    // rotated BEV corners (CCW order)
    float Axc[4], Azc[4], Bxc[4], Bzc[4];
    {
        float c = __cosf(a_ry), s = __sinf(a_ry);
        float hx = a_dx * 0.5f, hz = a_dz * 0.5f;
        const float lx[4] = { hx, -hx, -hx, hx };
        const float lz[4] = { hz, hz, -hz, -hz };
        #pragma unroll
        for (int k = 0; k < 4; k++) {
            Axc[k] = lx[k] * c - lz[k] * s + a_x;
            Azc[k] = lx[k] * s + lz[k] * c + a_z;
        }
    }
    {
        float c = __cosf(b_ry), s = __sinf(b_ry);
        float hx = b_dx * 0.5f, hz = b_dz * 0.5f;
        const float lx[4] = { hx, -hx, -hx, hx };
        const float lz[4] = { hz, hz, -hz, -hz };
        #pragma unroll
        for (int k = 0; k < 4; k++) {
            Bxc[k] = lx[k] * c - lz[k] * s + b_x;
            Bzc[k] = lx[k] * s + lz[k] * c + b_z;
        }
    }

    // quad areas (shoelace)
    float area_a = 0.0f, area_b = 0.0f;
    #pragma unroll
    for (int k = 0; k < 4; k++) {
        int kn = (k + 1) & 3;
        area_a += xprod(Axc[k], Azc[k], Axc[kn], Azc[kn]);
        area_b += xprod(Bxc[k], Bzc[k], Bxc[kn], Bzc[kn]);
    }
    area_a = 0.5f * fabsf(area_a);
    area_b = 0.5f * fabsf(area_b);

    // --- Sutherland-Hodgman: clip A by B's 4 half-planes (both CCW) ---
    float Px[8], Pz[8], Qx[8], Qz[8];
    #pragma unroll
    for (int k = 0; k < 8; k++) { Px[k] = 0.f; Pz[k] = 0.f; Qx[k] = 0.f; Qz[k] = 0.f; }
    #pragma unroll
    for (int k = 0; k < 4; k++) { Px[k] = Axc[k]; Pz[k] = Azc[k]; }
    int n = 4;

    n = clip_pass<4>(Px, Pz, n, Bxc[0], Bzc[0], Bxc[1] - Bxc[0], Bzc[1] - Bzc[0], Qx, Qz);
    n = clip_pass<5>(Qx, Qz, n, Bxc[1], Bzc[1], Bxc[2] - Bxc[1], Bzc[2] - Bzc[1], Px, Pz);
    n = clip_pass<6>(Px, Pz, n, Bxc[2], Bzc[2], Bxc[3] - Bxc[2], Bzc[3] - Bzc[2], Qx, Qz);
    n = clip_pass<7>(Qx, Qz, n, Bxc[3], Bzc[3], Bxc[0] - Bxc[3], Bzc[0] - Bzc[3], Px, Pz);

    // shoelace over the n-vertex clipped polygon (in Px/Pz)
    float area2 = 0.0f;
    #pragma unroll
    for (int j = 0; j < 8; j++) {
        bool act = (j < n);
        bool last = (j == n - 1);
        float sx = last ? Px[0] : Px[(j + 1 < 8) ? j + 1 : 0];
        float sz = last ? Pz[0] : Pz[(j + 1 < 8) ? j + 1 : 0];
        float c = xprod(Px[j], Pz[j], sx, sz);
        area2 += act ? c : 0.0f;
    }
    float area = 0.5f * fabsf(area2);
    area = (n >= 3) ? area : 0.0f;

    float overlap3d = area * h_ov;
    float union3d = area_a * h_a0 + area_b * (max_h_b - min_h_b) - overlap3d;
    out[i] = overlap3d / union3d;
}

extern "C" void kernel_launch(void* const* d_in, const int* in_sizes, int n_in,
                              void* d_out, int out_size, void* d_ws, size_t ws_size,
                              hipStream_t stream) {
    const float* pred = (const float*)d_in[0];
    const float* tgt  = (const float*)d_in[1];
    float* out = (float*)d_out;
    int N = in_sizes[0] / 7;
    int block = 256;
    int grid = (N + block - 1) / block;
    hipLaunchKernelGGL(iou3d_kernel, dim3(grid), dim3(block), 0, stream,
                       pred, tgt, out, N);
}

// Round 3
// 69.268 us; speedup vs baseline: 4.7662x; 1.0775x over previous
//
#include <hip/hip_runtime.h>
#include <math.h>

static __device__ __forceinline__ float xprod(float ux, float uz, float vx, float vz) {
    return ux * vz - uz * vx;
}

// Sum of Green's-theorem contributions of polygon P's edges clipped to
// polygon Q's interior (both CCW quads). Each edge's visible sub-segment
// [t_lo, t_hi] is found by interval-clipping against Q's 4 half-planes;
// its boundary-integral contribution is cross(P(t_lo), P(t_hi)).
// Contributions are order-independent, so no polygon construction needed.
static __device__ __forceinline__ float edge_contrib(
    const float (&Pxc)[4], const float (&Pzc)[4],
    const float (&Qxc)[4], const float (&Qzc)[4])
{
    // Q plane data: edge vector e_j, offset c_j so that d(p) = ex*pz - ez*px - c_j
    float ex[4], ez[4], ec[4];
    #pragma unroll
    for (int j = 0; j < 4; j++) {
        int jn = (j + 1) & 3;
        ex[j] = Qxc[jn] - Qxc[j];
        ez[j] = Qzc[jn] - Qzc[j];
        ec[j] = ex[j] * Qzc[j] - ez[j] * Qxc[j];
    }

    // d-matrix: P vertex i vs Q plane j (16 values, registers)
    float d[4][4];
    #pragma unroll
    for (int i = 0; i < 4; i++) {
        #pragma unroll
        for (int j = 0; j < 4; j++) {
            d[i][j] = ex[j] * Pzc[i] - ez[j] * Pxc[i] - ec[j];
        }
    }

    float acc = 0.0f;
    #pragma unroll
    for (int i = 0; i < 4; i++) {
        int in_ = (i + 1) & 3;
        float t_lo = 0.0f, t_hi = 1.0f;
        #pragma unroll
        for (int j = 0; j < 4; j++) {
            float d0 = d[i][j], d1 = d[in_][j];
            float den = d0 - d1;                    // -slope
            float t = __fdividef(d0, (den == 0.0f) ? 1.0f : den);
            // den<0: d increasing -> entering plane (t* <= 0 when already inside)
            t_lo = (den < 0.0f) ? fmaxf(t_lo, t) : t_lo;
            // den>0: d decreasing -> leaving plane
            t_hi = (den > 0.0f) ? fminf(t_hi, t) : t_hi;
            // parallel & outside -> empty interval
            t_lo = (den == 0.0f && d0 < 0.0f) ? 1e9f : t_lo;
        }
        bool valid = t_lo < t_hi;
        float ax = Pxc[i], az = Pzc[i];
        float dx = Pxc[in_] - ax, dz = Pzc[in_] - az;
        float p0x = ax + t_lo * dx, p0z = az + t_lo * dz;
        float p1x = ax + t_hi * dx, p1z = az + t_hi * dz;
        float c = xprod(p0x, p0z, p1x, p1z);
        acc += valid ? c : 0.0f;
    }
    return acc;
}

__global__ __launch_bounds__(256) void iou3d_kernel(
    const float* __restrict__ pred,
    const float* __restrict__ tgt,
    float* __restrict__ out,
    int N)
{
    int i = blockIdx.x * blockDim.x + threadIdx.x;
    if (i >= N) return;

    const float* pa = pred + (long)i * 7;
    const float* pb = tgt  + (long)i * 7;

    float a_x  = pa[0], a_y = pa[1], a_z = pa[2];
    float a_dx = pa[3], a_dy = pa[4], a_dz = pa[5], a_ry = pa[6];
    float b_x  = pb[0], b_y = pb[1], b_z = pb[2];
    float b_dx = pb[3], b_dy = pb[4], b_dz = pb[5], b_ry = pb[6];

    // height overlap (reference: y axis negated, clip at 0)
    float min_h_a = -(a_y + a_dy * 0.5f);
    float max_h_a = -(a_y - a_dy * 0.5f);
    float min_h_b = -(b_y + b_dy * 0.5f);
    float max_h_b = -(b_y - b_dy * 0.5f);
    float h_ov = fmaxf(fminf(max_h_a, max_h_b) - fmaxf(min_h_a, min_h_b), 0.0f);

    // reference quirk: h_a0 is box 0's pred height for ALL rows
    float y0 = pred[1], dy0 = pred[4];
    float h_a0 = (-(y0 - dy0 * 0.5f)) - (-(y0 + dy0 * 0.5f));

    // local frame: translate by midpoint of centers (area-invariant,
    // kills fp32 cancellation in cross products at |coord|~60)
    float mx = 0.5f * (a_x + b_x);
    float mz = 0.5f * (a_z + b_z);
    float ax0 = a_x - mx, az0 = a_z - mz;
    float bx0 = b_x - mx, bz0 = b_z - mz;

    // rotated BEV corners (CCW)
    float Axc[4], Azc[4], Bxc[4], Bzc[4];
    {
        float c = __cosf(a_ry), s = __sinf(a_ry);
        float hx = a_dx * 0.5f, hz = a_dz * 0.5f;
        const float lx[4] = { hx, -hx, -hx, hx };
        const float lz[4] = { hz, hz, -hz, -hz };
        #pragma unroll
        for (int k = 0; k < 4; k++) {
            Axc[k] = lx[k] * c - lz[k] * s + ax0;
            Azc[k] = lx[k] * s + lz[k] * c + az0;
        }
    }
    {
        float c = __cosf(b_ry), s = __sinf(b_ry);
        float hx = b_dx * 0.5f, hz = b_dz * 0.5f;
        const float lx[4] = { hx, -hx, -hx, hx };
        const float lz[4] = { hz, hz, -hz, -hz };
        #pragma unroll
        for (int k = 0; k < 4; k++) {
            Bxc[k] = lx[k] * c - lz[k] * s + bx0;
            Bzc[k] = lx[k] * s + lz[k] * c + bz0;
        }
    }

    // quad areas: exact (dx*dz), matches shoelace of a rectangle
    float area_a = a_dx * a_dz;
    float area_b = b_dx * b_dz;

    // intersection area via boundary integral
    float acc = edge_contrib(Axc, Azc, Bxc, Bzc)   // A's edges inside B
              + edge_contrib(Bxc, Bzc, Axc, Azc);  // B's edges inside A
    float area = 0.5f * fabsf(acc);

    float overlap3d = area * h_ov;
    float union3d = area_a * h_a0 + area_b * (max_h_b - min_h_b) - overlap3d;
    out[i] = overlap3d / union3d;
}

extern "C" void kernel_launch(void* const* d_in, const int* in_sizes, int n_in,
                              void* d_out, int out_size, void* d_ws, size_t ws_size,
                              hipStream_t stream) {
    const float* pred = (const float*)d_in[0];
    const float* tgt  = (const float*)d_in[1];
    float* out = (float*)d_out;
    int N = in_sizes[0] / 7;
    int block = 256;
    int grid = (N + block - 1) / block;
    hipLaunchKernelGGL(iou3d_kernel, dim3(grid), dim3(block), 0, stream,
                       pred, tgt, out, N);
}

// Round 4
// 65.106 us; speedup vs baseline: 5.0709x; 1.0639x over previous
//
#include <hip/hip_runtime.h>
#include <math.h>

// Clip parameter interval of a segment (start (x0,z0), direction d with
// precomputed 1/dx, 1/dz) against the AABB slab |x|<=hx, |z|<=hz.
// Returns max(t_hi - t_lo, 0) over [0,1]. rcp(0)=inf flows through
// IEEE minNum/maxNum semantics of v_min/v_max correctly (parallel-inside ->
// unconstrained, parallel-outside -> empty).
static __device__ __forceinline__ float slab_dt(
    float x0, float z0, float ivx, float ivz, float hx, float hz)
{
    float t1 = (-hx - x0) * ivx;
    float t2 = ( hx - x0) * ivx;
    float t3 = (-hz - z0) * ivz;
    float t4 = ( hz - z0) * ivz;
    float nx = fminf(t1, t2), fx = fmaxf(t1, t2);
    float nz = fminf(t3, t4), fz = fmaxf(t3, t4);
    float tlo = fmaxf(fmaxf(nx, nz), 0.0f);   // v_max3
    float thi = fminf(fminf(fx, fz), 1.0f);   // v_min3
    return fmaxf(thi - tlo, 0.0f);
}

static __device__ __forceinline__ float rcpf(float x) {
    return __builtin_amdgcn_rcpf(x);
}

__global__ __launch_bounds__(256) void iou3d_kernel(
    const float* __restrict__ pred,
    const float* __restrict__ tgt,
    float* __restrict__ out,
    int N)
{
    int i = blockIdx.x * blockDim.x + threadIdx.x;
    if (i >= N) return;

    const float* pa = pred + (long)i * 7;
    const float* pb = tgt  + (long)i * 7;

    float a_x  = pa[0], a_y = pa[1], a_z = pa[2];
    float a_dx = pa[3], a_dy = pa[4], a_dz = pa[5], a_ry = pa[6];
    float b_x  = pb[0], b_y = pb[1], b_z = pb[2];
    float b_dx = pb[3], b_dy = pb[4], b_dz = pb[5], b_ry = pb[6];

    // height overlap (reference: y axis negated, clip at 0)
    float min_h_a = -(a_y + a_dy * 0.5f);
    float max_h_a = -(a_y - a_dy * 0.5f);
    float min_h_b = -(b_y + b_dy * 0.5f);
    float max_h_b = -(b_y - b_dy * 0.5f);
    float h_ov = fmaxf(fminf(max_h_a, max_h_b) - fmaxf(min_h_a, min_h_b), 0.0f);

    // reference quirk: h_a0 is box 0's pred height for ALL rows
    float y0 = pred[1], dy0 = pred[4];
    float h_a0 = (-(y0 - dy0 * 0.5f)) - (-(y0 + dy0 * 0.5f));

    // ---- A-local frame: A = AABB [-p,p]x[-q,q]; B rotated by theta=rb-ra ----
    float ca = __cosf(a_ry), sa = __sinf(a_ry);
    float cb = __cosf(b_ry), sb = __sinf(b_ry);
    float c  = cb * ca + sb * sa;     // cos(rb - ra)
    float sn = sb * ca - cb * sa;     // sin(rb - ra)
    float exw = b_x - a_x, ezw = b_z - a_z;
    float ox =  ca * exw + sa * ezw;  // R(-ra) * (cB - cA)
    float oz = -sa * exw + ca * ezw;

    float p = 0.5f * a_dx, q = 0.5f * a_dz;
    float r = 0.5f * b_dx, s = 0.5f * b_dz;

    // B axes scaled by half-extents: r*u, s*w (u=(c,sn), w=R90*u=(-sn,c))
    float ux = r * c,   uz = r * sn;
    float wx = -s * sn, wz = s * c;

    // B corners in A frame, CCW: o + [+,-,-,+]*ru + [+,+,-,-]*sw
    float B0x = ox + ux + wx, B0z = oz + uz + wz;
    float B1x = ox - ux + wx, B1z = oz - uz + wz;
    float B2x = ox - ux - wx, B2z = oz - uz - wz;
    float B3x = ox + ux - wx, B3z = oz + uz - wz;

    // ---- Part 1: B's edges clipped to A (AABB slabs). Edge vectors:
    // d0=-2(ux,uz), d1=-2(wx,wz), d2=+2(ux,uz), d3=+2(wx,wz)
    float i_ux = rcpf(ux), i_uz = rcpf(uz);
    float i_wx = rcpf(wx), i_wz = rcpf(wz);

    float dt0 = slab_dt(B0x, B0z, -0.5f * i_ux, -0.5f * i_uz, p, q);
    float dt1 = slab_dt(B1x, B1z, -0.5f * i_wx, -0.5f * i_wz, p, q);
    float dt2 = slab_dt(B2x, B2z,  0.5f * i_ux,  0.5f * i_uz, p, q);
    float dt3 = slab_dt(B3x, B3z,  0.5f * i_wx,  0.5f * i_wz, p, q);

    // Green contribution of edge k is dt_k * cross(Bk, dk); closed forms:
    // cross(B0,d0)=2rs-2r*D1, cross(B1,d1)=2rs-2s*D2,
    // cross(B2,d2)=2rs+2r*D1, cross(B3,d3)=2rs+2s*D2,
    // with D1=cross(o,u), D2=dot(o,u) (u unit).
    float D1 = ox * sn - oz * c;
    float D2 = ox * c + oz * sn;
    float rs = r * s;
    float part1 = 2.0f * (rs * (dt0 + dt1 + dt2 + dt3)
                        + r * D1 * (dt2 - dt0)
                        + s * D2 * (dt3 - dt1));

    // ---- Part 2: A's edges clipped to B. In B's (u,w) coordinates the
    // problem is again AABB-slab clipping with extents (r,s).
    // A corners CCW: A0=(p,q), A1=(-p,q), A2=(-p,-q), A3=(p,-q);
    // fu(V)=dot(V-o,u), fw(V)=dot(V-o,w) expand via Pc,Psn,Qc,Qsn,D1,D2.
    float Pc = p * c, Psn = p * sn, Qc = q * c, Qsn = q * sn;
    float i_Pc = rcpf(Pc), i_Psn = rcpf(Psn);
    float i_Qc = rcpf(Qc), i_Qsn = rcpf(Qsn);

    float fu0 =  Pc + Qsn - D2, fw0 = -Psn + Qc + D1;  // A0
    float fu1 = -Pc + Qsn - D2, fw1 =  Psn + Qc + D1;  // A1
    float fu2 = -Pc - Qsn - D2, fw2 =  Psn - Qc + D1;  // A2
    float fu3 =  Pc - Qsn - D2, fw3 = -Psn - Qc + D1;  // A3

    // Edge slopes in (u,w) coords:
    // e0 d=(-2p,0): su=-2Pc, sw=+2Psn;  e1 d=(0,-2q): su=-2Qsn, sw=-2Qc
    // e2 d=(+2p,0): su=+2Pc, sw=-2Psn;  e3 d=(0,+2q): su=+2Qsn, sw=+2Qc
    float dA0 = slab_dt(fu0, fw0, -0.5f * i_Pc,   0.5f * i_Psn, r, s);
    float dA1 = slab_dt(fu1, fw1, -0.5f * i_Qsn, -0.5f * i_Qc,  r, s);
    float dA2 = slab_dt(fu2, fw2,  0.5f * i_Pc,  -0.5f * i_Psn, r, s);
    float dA3 = slab_dt(fu3, fw3,  0.5f * i_Qsn,  0.5f * i_Qc,  r, s);

    // cross(A_k, d_k) = 2pq for all four edges
    float part2 = 2.0f * p * q * (dA0 + dA1 + dA2 + dA3);

    float area = 0.5f * fabsf(part1 + part2);

    float area_a = a_dx * a_dz;
    float area_b = b_dx * b_dz;

    float overlap3d = area * h_ov;
    float union3d = area_a * h_a0 + area_b * (max_h_b - min_h_b) - overlap3d;
    out[i] = overlap3d / union3d;
}

extern "C" void kernel_launch(void* const* d_in, const int* in_sizes, int n_in,
                              void* d_out, int out_size, void* d_ws, size_t ws_size,
                              hipStream_t stream) {
    const float* pred = (const float*)d_in[0];
    const float* tgt  = (const float*)d_in[1];
    float* out = (float*)d_out;
    int N = in_sizes[0] / 7;
    int block = 256;
    int grid = (N + block - 1) / block;
    hipLaunchKernelGGL(iou3d_kernel, dim3(grid), dim3(block), 0, stream,
                       pred, tgt, out, N);
}